// Round 1
// baseline (82.411 us; speedup 1.0000x reference)
//
#include <hip/hip_runtime.h>

constexpr int B_ = 4;
constexpr int L_ = 4096;
constexpr int D_ = 128;
constexpr int K_ = 16;

// One block per query row (b, i). Thread 0 computes the exact top-K
// (distance, index) neighbor list (replicating jax.lax.top_k tie-breaking:
// ascending d2, ties by ascending index); all 128 threads then gather the
// K x D attr rows with float4 loads/stores.
__global__ __launch_bounds__(128) void local_nbr_kernel(
    const int* __restrict__ fi, const float* __restrict__ attr,
    float* __restrict__ out_dist, float* __restrict__ out_attr)
{
    const int q = blockIdx.x;           // [0, B*L)
    const int b = q >> 12;              // q / L_
    const int i = q & (L_ - 1);         // q % L_
    const int* __restrict__ c = fi + b * L_;

    __shared__ int s_nbr[K_];
    __shared__ int s_ci;
    __shared__ int s_cand[2 * K_];
    __shared__ int s_cd[2 * K_];

    if (threadIdx.x == 0) {
        const int ci = c[i];
        s_ci = ci;

        // --- greedy two-pointer: 16-wide window achieving the 16-smallest
        // distance multiset (contains ALL elements with dist < T).
        int lo = i, hi = i;
        for (int t = 0; t < K_ - 1; ++t) {
            int dl = (lo > 0)      ? (ci - c[lo - 1]) : 0x7FFFFFFF;
            int dr = (hi < L_ - 1) ? (c[hi + 1] - ci) : 0x7FFFFFFF;
            if (dl <= dr) --lo; else ++hi;
        }
        const int T = max(ci - c[lo], c[hi] - ci);

        // --- candidates: the window itself...
        int ncand = 0;
        for (int j = lo; j <= hi; ++j) {
            int v = c[j];
            s_cand[ncand] = j;
            s_cd[ncand]   = (v < ci) ? (ci - v) : (v - ci);
            ++ncand;
        }
        // ...plus the left tie-run (value ci - T) extending left of the
        // window: those have dist == T but SMALLER indices, so top_k's
        // tie-break can prefer them. (Right-of-window ties have larger
        // indices than every in-window tie and can never be selected.)
        const int vL = ci - T;
        int j0 = -1;
        if (c[lo] == vL) j0 = lo;
        else if (lo > 0 && c[lo - 1] == vL) j0 = lo - 1;
        if (j0 >= 0) {
            int p = j0;
            while (p > 0 && c[p - 1] == vL) --p;   // run start (smallest idx)
            const int e = min(lo - 1, p + (K_ - 1));
            for (int j = p; j <= e; ++j) {
                s_cand[ncand] = j;
                s_cd[ncand]   = T;
                ++ncand;
            }
        }

        // --- exact top-K by (dist, index) ascending: partial selection sort
        for (int s = 0; s < K_; ++s) {
            int best = s;
            for (int t2 = s + 1; t2 < ncand; ++t2) {
                if (s_cd[t2] < s_cd[best] ||
                    (s_cd[t2] == s_cd[best] && s_cand[t2] < s_cand[best]))
                    best = t2;
            }
            int ti = s_cand[s]; s_cand[s] = s_cand[best]; s_cand[best] = ti;
            int td = s_cd[s];   s_cd[s]   = s_cd[best];   s_cd[best]   = td;
            s_nbr[s] = s_cand[s];
        }
    }
    __syncthreads();

    // --- output 0: index_distance [B, L, K, 1] (exact: |int diff| as f32)
    if (threadIdx.x < K_) {
        int j = s_nbr[threadIdx.x];
        int d = c[j] - s_ci;
        if (d < 0) d = -d;
        out_dist[(size_t)q * K_ + threadIdx.x] = (float)d;
    }

    // --- output 1: attr_nb [B, L, K, D] gathered as float4
    const float4* __restrict__ src = (const float4*)(attr + (size_t)b * L_ * D_);
    float4* __restrict__ dst = (float4*)(out_attr + (size_t)q * (K_ * D_));
    const int t = threadIdx.x;
    #pragma unroll
    for (int pass = 0; pass < (K_ * D_ / 4) / 128; ++pass) {  // 4 passes
        int f4 = pass * 128 + t;
        int k  = f4 >> 5;        // / 32  (float4s per row = 32)
        int d4 = f4 & 31;
        int j  = s_nbr[k];
        dst[f4] = src[j * (D_ / 4) + d4];
    }
}

extern "C" void kernel_launch(void* const* d_in, const int* in_sizes, int n_in,
                              void* d_out, int out_size, void* d_ws, size_t ws_size,
                              hipStream_t stream) {
    const int*   fi   = (const int*)d_in[0];     // [B, L, 1] int32 (sorted per b)
    const float* attr = (const float*)d_in[1];   // [B, L, D] float32
    float* out      = (float*)d_out;
    float* out_dist = out;                        // [B, L, K, 1]
    float* out_attr = out + (size_t)B_ * L_ * K_; // [B, L, K, D]

    dim3 grid(B_ * L_);
    dim3 block(128);
    local_nbr_kernel<<<grid, block, 0, stream>>>(fi, attr, out_dist, out_attr);
}

// Round 2
// 33.408 us; speedup vs baseline: 2.4668x; 2.4668x over previous
//
#include <hip/hip_runtime.h>

constexpr int B_ = 4;
constexpr int L_ = 4096;
constexpr int D_ = 128;
constexpr int K_ = 16;
constexpr int NKEY = 2 * K_;          // 32 candidates max
constexpr int GATHER_BLOCKS = 2048;   // 8 blocks/CU on 256 CUs
constexpr int F4_TOTAL = B_ * L_ * K_ * (D_ / 4);       // 8,388,608 float4
constexpr int F4_PER_BLOCK = F4_TOTAL / GATHER_BLOCKS;  // 4096
constexpr int GATHER_ITERS = F4_PER_BLOCK / 256;        // 16

static __device__ __forceinline__ int imin(int a, int b) { return a < b ? a : b; }
static __device__ __forceinline__ int imax(int a, int b) { return a > b ? a : b; }

// ---------------- kernel 1: exact top-K search, one query per thread -------
// Packs (dist, idx) into a single int key = (dist<<12)|idx  (dist < 2^18,
// idx < 2^12), so ascending key order == ascending (dist, idx) — exactly
// jax.lax.top_k's tie-breaking. Writes keys into out_dist's storage (as int);
// the gather kernel converts them to float distances in place each call.
__global__ __launch_bounds__(64) void nbr_search_kernel(
    const int* __restrict__ fi, int* __restrict__ keyout)
{
    const int q = blockIdx.x * 64 + threadIdx.x;     // [0, B*L)
    const int b = q >> 12;
    const int i = q & (L_ - 1);
    const int* __restrict__ c = fi + b * L_;
    const int ci = c[i];

    // greedy two-pointer: exact 16-wide window holding the 16-smallest
    // distance multiset (contains ALL elements with dist < T)
    int lo = i, hi = i;
    #pragma unroll
    for (int t = 0; t < K_ - 1; ++t) {
        int dl = (lo > 0)      ? (ci - c[lo - 1]) : 0x7FFFFFFF;
        int dr = (hi < L_ - 1) ? (c[hi + 1] - ci) : 0x7FFFFFFF;
        if (dl <= dr) --lo; else ++hi;
    }
    const int T = imax(ci - c[lo], c[hi] - ci);

    int keys[NKEY];                    // static-indexed only (no scratch)
    #pragma unroll
    for (int t = 0; t < K_; ++t) {
        int j = lo + t;
        int v = c[j];
        int d = (v < ci) ? (ci - v) : (v - ci);
        keys[t] = (d << 12) | j;
    }

    // left tie-run: elements of value ci-T left of the window have dist == T
    // with SMALLER indices than any in-window tie -> top_k can prefer them.
    const int vL = ci - T;
    int j0 = -1;
    if (c[lo] == vL) j0 = lo;
    else if (lo > 0 && c[lo - 1] == vL) j0 = lo - 1;
    #pragma unroll
    for (int t = 0; t < K_; ++t) keys[K_ + t] = 0x7FFFFFFF;
    if (j0 >= 0) {
        int p = j0;
        while (p > 0 && c[p - 1] == vL) --p;         // run start (min index)
        const int e = imin(lo - 1, p + (K_ - 1));
        #pragma unroll
        for (int t = 0; t < K_; ++t) {
            int j = p + t;
            if (j <= e) keys[K_ + t] = (T << 12) | j;
        }
    }

    // bitonic sort, 32 keys, fully unrolled (static indices -> registers)
    #pragma unroll
    for (int size = 2; size <= NKEY; size <<= 1) {
        #pragma unroll
        for (int stride = size >> 1; stride > 0; stride >>= 1) {
            #pragma unroll
            for (int x = 0; x < NKEY; ++x) {
                int y = x ^ stride;
                if (y > x) {
                    bool up = ((x & size) == 0);
                    int a = keys[x], bb = keys[y];
                    int mn = imin(a, bb), mx = imax(a, bb);
                    keys[x] = up ? mn : mx;
                    keys[y] = up ? mx : mn;
                }
            }
        }
    }

    int4* ko = (int4*)(keyout + (size_t)q * K_);
    ko[0] = make_int4(keys[0],  keys[1],  keys[2],  keys[3]);
    ko[1] = make_int4(keys[4],  keys[5],  keys[6],  keys[7]);
    ko[2] = make_int4(keys[8],  keys[9],  keys[10], keys[11]);
    ko[3] = make_int4(keys[12], keys[13], keys[14], keys[15]);
}

// ---------------- kernel 2: streaming gather, XCD-swizzled ----------------
// Each block copies a CONTIGUOUS 4096-float4 (64 KB) output slice; the XCD
// swizzle gives each XCD a contiguous q-range so its attr working set
// (~1 MB) fits the 4 MB per-XCD L2. 32 lanes handle one K-row (512 B).
__global__ __launch_bounds__(256) void nbr_gather_kernel(
    const float* __restrict__ attr, float* __restrict__ out_dist,
    float* __restrict__ out_attr)
{
    const int bid  = blockIdx.x;
    const int sbid = (bid & 7) * (GATHER_BLOCKS / 8) + (bid >> 3);
    const int tid  = threadIdx.x;
    const int* __restrict__ keys = (const int*)out_dist;  // same storage
    const size_t base = (size_t)sbid * F4_PER_BLOCK;

    #pragma unroll 2
    for (int it = 0; it < GATHER_ITERS; ++it) {
        size_t f4 = base + (size_t)it * 256 + tid;
        int row = (int)(f4 >> 5);          // global (q,k) row, 32 f4 per row
        int off = (int)(f4 & 31);
        int key = keys[row];               // broadcast across the 32 lanes
        int j   = key & (L_ - 1);
        int bb  = row >> 16;               // row / (L_*K_)
        const float4* __restrict__ src =
            (const float4*)attr + ((size_t)bb * L_ + j) * (D_ / 4);
        ((float4*)out_attr)[f4] = src[off];
        if (off == 0)                      // finalize distance in place
            out_dist[row] = (float)(key >> 12);
    }
}

extern "C" void kernel_launch(void* const* d_in, const int* in_sizes, int n_in,
                              void* d_out, int out_size, void* d_ws, size_t ws_size,
                              hipStream_t stream) {
    const int*   fi   = (const int*)d_in[0];     // [B, L, 1] int32 (sorted per b)
    const float* attr = (const float*)d_in[1];   // [B, L, D] float32
    float* out      = (float*)d_out;
    float* out_dist = out;                        // [B, L, K, 1]
    float* out_attr = out + (size_t)B_ * L_ * K_; // [B, L, K, D]

    nbr_search_kernel<<<dim3(B_ * L_ / 64), dim3(64), 0, stream>>>(
        fi, (int*)out_dist);
    nbr_gather_kernel<<<dim3(GATHER_BLOCKS), dim3(256), 0, stream>>>(
        attr, out_dist, out_attr);
}